// Round 3
// baseline (547.855 us; speedup 1.0000x reference)
//
#include <hip/hip_runtime.h>
#include <hip/hip_bf16.h>
#include <math.h>

// GPT decoder layer, MI355X/gfx950. bf16 MFMA GEMMs + fused flash attention.
// B=4 S=2048 D=1024 H=16 DH=64 F=4096.  Workspace layout (bytes):
//   [0,6M)      WqkvT  bf16 [3072][1024]   (pre-transposed, k-contiguous)
//   [6M,8M)     WoT    bf16 [1024][1024]
//   [8M,16M)    W1T    bf16 [4096][1024]
//   [16M,24M)   W2T    bf16 [1024][4096]
//   [24M,40M)   hbuf   bf16 [8192][1024]   (h -> attn_out -> h2, reused)
//   [40M,104M)  big    bf16                (QKV [8192][3072], later ff1 [8192][4096])

#define Bz 4
#define Sz 2048
#define Dz 1024
#define Hz 16
#define DHz 64
#define Fz 4096
#define Mz 8192

typedef float f32x4 __attribute__((ext_vector_type(4)));
typedef __bf16 bf16x8 __attribute__((ext_vector_type(8)));
typedef __bf16 bf16x4 __attribute__((ext_vector_type(4)));
typedef short s16x4 __attribute__((ext_vector_type(4)));

#define GLOAD_LDS16(g, l)                                                                   \
  __builtin_amdgcn_global_load_lds((const __attribute__((address_space(1))) unsigned int*)(g), \
                                   (__attribute__((address_space(3))) unsigned int*)(l), 16, 0, 0)

static __device__ __forceinline__ unsigned short f2bu(float f) {
  unsigned int u = __float_as_uint(f);
  u += 0x7fffu + ((u >> 16) & 1u);   // RNE to bf16
  return (unsigned short)(u >> 16);
}

static __device__ __forceinline__ f32x4 mfma32(bf16x8 a, bf16x8 b, f32x4 c) {
  return __builtin_amdgcn_mfma_f32_16x16x32_bf16(a, b, c, 0, 0, 0);
}
static __device__ __forceinline__ f32x4 mfma16(s16x4 a, s16x4 b, f32x4 c) {
#if __has_builtin(__builtin_amdgcn_mfma_f32_16x16x16bf16_1k)
  return __builtin_amdgcn_mfma_f32_16x16x16bf16_1k(a, b, c, 0, 0, 0);
#else
  asm("v_mfma_f32_16x16x16_bf16 %0, %1, %2, %0" : "+v"(c) : "v"(a), "v"(b));
  return c;
#endif
}

// hardware transpose read: lane l elem j <- lds[base + (l&15) + j*16 + (l>>4)*64] (bf16 elems)
template <int OFF>
static __device__ __forceinline__ s16x4 tr16(unsigned addr) {
  s16x4 r;
  asm volatile("ds_read_b64_tr_b16 %0, %1 offset:%2" : "=v"(r) : "v"(addr), "i"(OFF));
  return r;
}

// ---------------- weight packing ----------------

__global__ __launch_bounds__(256) void pack_qkv(
    const float* __restrict__ wq, const float* __restrict__ wk, const float* __restrict__ wv,
    unsigned short* __restrict__ outW)  // [3072][1024], row n = proj*1024 + h*64 + e, col = d
{
  __shared__ float tile[64][65];
  const int blk = blockIdx.x;       // 768 = 16 dchunk x 16 h x 3 proj
  const int dc = blk & 15;
  const int h  = (blk >> 4) & 15;
  const int p  = blk >> 8;
  const float* w = p == 0 ? wq : (p == 1 ? wk : wv);
  const int tid = threadIdx.x;
#pragma unroll
  for (int i = 0; i < 4; ++i) {
    int idx = i * 256 + tid;
    int dl = idx >> 4;
    int e0 = (idx & 15) * 4;
    const float4 v = *(const float4*)&w[(size_t)(h * 1024 + dc * 64 + dl) * 64 + e0];
    tile[dl][e0 + 0] = v.x; tile[dl][e0 + 1] = v.y;
    tile[dl][e0 + 2] = v.z; tile[dl][e0 + 3] = v.w;
  }
  __syncthreads();
#pragma unroll
  for (int i = 0; i < 4; ++i) {
    int idx = i * 256 + tid;
    int e = idx >> 4;
    int d0 = (idx & 15) * 4;
    ushort4 o;
    o.x = f2bu(tile[d0 + 0][e]); o.y = f2bu(tile[d0 + 1][e]);
    o.z = f2bu(tile[d0 + 2][e]); o.w = f2bu(tile[d0 + 3][e]);
    *(ushort4*)&outW[(size_t)(p * 1024 + h * 64 + e) * 1024 + dc * 64 + d0] = o;
  }
}

__global__ __launch_bounds__(256) void transpose_f32_to_bf16(
    const float* __restrict__ in, unsigned short* __restrict__ out, int R, int C)
{ // in [R][C] fp32 -> out [C][R] bf16
  __shared__ float tile[32][33];
  int c0 = blockIdx.x * 32, r0 = blockIdx.y * 32;
  int x = threadIdx.x, y = threadIdx.y;
#pragma unroll
  for (int i = 0; i < 32; i += 8)
    tile[y + i][x] = in[(size_t)(r0 + y + i) * C + c0 + x];
  __syncthreads();
#pragma unroll
  for (int i = 0; i < 32; i += 8)
    out[(size_t)(c0 + y + i) * R + r0 + x] = f2bu(tile[x][y + i]);
}

// ---------------- layernorm ----------------

__global__ __launch_bounds__(256) void ln_kernel(
    const float* __restrict__ x, const float* __restrict__ gamma, const float* __restrict__ beta,
    unsigned short* __restrict__ outH)
{
  const int row = blockIdx.x;
  const int tid = threadIdx.x;
  const float4 v = ((const float4*)(x + (size_t)row * Dz))[tid];
  float s = v.x + v.y + v.z + v.w;
  float s2 = v.x * v.x + v.y * v.y + v.z * v.z + v.w * v.w;
#pragma unroll
  for (int o = 32; o > 0; o >>= 1) {
    s += __shfl_xor(s, o);
    s2 += __shfl_xor(s2, o);
  }
  __shared__ float ss[4], ss2[4];
  if ((tid & 63) == 0) { ss[tid >> 6] = s; ss2[tid >> 6] = s2; }
  __syncthreads();
  s = ss[0] + ss[1] + ss[2] + ss[3];
  s2 = ss2[0] + ss2[1] + ss2[2] + ss2[3];
  const float mean = s * (1.0f / Dz);
  const float rstd = rsqrtf(s2 * (1.0f / Dz) - mean * mean + 1e-5f);
  const float4 g4 = ((const float4*)gamma)[tid];
  const float4 b4 = ((const float4*)beta)[tid];
  ushort4 o;
  o.x = f2bu((v.x - mean) * rstd * g4.x + b4.x);
  o.y = f2bu((v.y - mean) * rstd * g4.y + b4.y);
  o.z = f2bu((v.z - mean) * rstd * g4.z + b4.z);
  o.w = f2bu((v.w - mean) * rstd * g4.w + b4.w);
  ((ushort4*)(outH + (size_t)row * Dz))[tid] = o;
}

// ---------------- GEMM: C[M,N] = A[M,K](bf16) @ BT[N,K]^T(bf16), m97-style ----------------

enum { EPI_BF16 = 0, EPI_GELU_BF16 = 1, EPI_RES_F32 = 2, EPI_BIAS_RES_F32 = 3 };

template <int EPI>
__global__ __launch_bounds__(256) void gemm_kernel(
    const unsigned short* __restrict__ A,   // [M,K] bf16
    const unsigned short* __restrict__ BT,  // [N,K] bf16
    int M, int N, int K,
    const float* bias, const float* resid,  // resid/outf may alias: no __restrict__
    unsigned short* outb, float* outf)
{
  __shared__ unsigned short As[128 * 32];  // [row][32k], 16B chunk c XOR-swizzled by row&3
  __shared__ unsigned short Bs[128 * 32];
  const int tid = threadIdx.x;
  const int lane = tid & 63;
  const int m0 = blockIdx.y * 128;
  const int n0 = blockIdx.x * 128;
  const int wm = ((tid >> 7) & 1) * 64;
  const int wn = ((tid >> 6) & 1) * 64;
  const int rsel = lane & 15;
  const int kgrp = lane >> 4;

  f32x4 acc[4][4] = {};

  const int kTiles = K >> 5;
  for (int kt = 0; kt < kTiles; ++kt) {
    if (kt) __syncthreads();
    const int kOff = kt * 32;
#pragma unroll
    for (int r = 0; r < 2; ++r) {
      int c = r * 256 + tid;           // 512 chunks of 16B per tile
      int row = c >> 2;
      int kcs = (c & 3) ^ (row & 3);   // pre-swizzled global source, linear LDS dest
      GLOAD_LDS16(A + (size_t)(m0 + row) * K + kOff + kcs * 8, &As[c * 8]);
      GLOAD_LDS16(BT + (size_t)(n0 + row) * K + kOff + kcs * 8, &Bs[c * 8]);
    }
    __syncthreads();
    bf16x8 af[4], bfr[4];
#pragma unroll
    for (int mf = 0; mf < 4; ++mf) {
      int row = wm + mf * 16 + rsel;
      af[mf] = *(const bf16x8*)&As[row * 32 + ((kgrp ^ (row & 3)) * 8)];
    }
#pragma unroll
    for (int nf = 0; nf < 4; ++nf) {
      int row = wn + nf * 16 + rsel;
      bfr[nf] = *(const bf16x8*)&Bs[row * 32 + ((kgrp ^ (row & 3)) * 8)];
    }
#pragma unroll
    for (int mf = 0; mf < 4; ++mf)
#pragma unroll
      for (int nf = 0; nf < 4; ++nf)
        acc[mf][nf] = mfma32(af[mf], bfr[nf], acc[mf][nf]);
  }

#pragma unroll
  for (int mf = 0; mf < 4; ++mf) {
#pragma unroll
    for (int nf = 0; nf < 4; ++nf) {
      const int n = n0 + wn + nf * 16 + rsel;
#pragma unroll
      for (int j = 0; j < 4; ++j) {
        const int m = m0 + wm + mf * 16 + kgrp * 4 + j;
        const size_t idx = (size_t)m * N + n;
        float v = acc[mf][nf][j];
        if constexpr (EPI == EPI_BF16) {
          outb[idx] = f2bu(v);
        } else if constexpr (EPI == EPI_GELU_BF16) {
          v += bias[n];
          v = 0.5f * v * (1.0f + erff(v * 0.70710678118654752f));
          outb[idx] = f2bu(v);
        } else if constexpr (EPI == EPI_RES_F32) {
          outf[idx] = v + resid[idx];
        } else {
          outf[idx] = v + bias[n] + resid[idx];
        }
      }
    }
  }
}

// ---------------- fused causal flash attention ----------------
// Block = pair of q-tiles {pi, 31-pi} x (b,h): 33 compute-tiles per block (perfect
// balance), pair shares K/V staging. 1D grid, XCD-grouped: the 16 blocks sharing a
// (b,h) K/V stream land on one XCD's L2. K/V double-buffered: stage kt+1 issued
// BEFORE computing kt, one vmcnt(0)+barrier per iter (T3-minimum).
// S^T = K @ Q^T via mfma 16x16x32; P^T stays in registers as the B-frag of
// mfma 16x16x16 for O^T = V^T @ P^T; V read with ds_read_b64_tr_b16.
// Softmax in log2 domain with defer-rescale (THR=8).

__global__ __launch_bounds__(256, 4) void attn_kernel(
    const unsigned short* __restrict__ QKV,  // [Mz][3072] bf16 (q|k|v, feature h*64+e)
    unsigned short* __restrict__ outA)       // [Mz][Dz]  bf16
{
  __shared__ unsigned short Kt[2][64 * 64];  // [key][d], 16B d-chunk XOR-swizzled by key&7
  __shared__ unsigned short Vs[2][64 * 64];  // subtiled for tr16 reads
  const int bid = blockIdx.x;
  const int xcd = bid & 7;
  const int t = bid >> 3;
  const int pi = t & 15;
  const int g = xcd * 8 + (t >> 4);  // 64 groups; 8 per XCD (4MB K/V per L2)
  const int hh = g & 15;
  const int bb = g >> 4;
  const int tid = threadIdx.x;
  const int lane = tid & 63;
  const int w = tid >> 6;
  const int rsel = lane & 15;
  const int kgrp = lane >> 4;
  const int qtA = pi, qtB = 31 - pi;
  const int qgA = qtA * 64 + w * 16 + rsel;
  const int qgB = qtB * 64 + w * 16 + rsel;
  const size_t rowQA = (size_t)(bb * Sz + qgA) * 3072 + hh * 64;
  const size_t rowQB = (size_t)(bb * Sz + qgB) * 3072 + hh * 64;

  const bf16x8 qfA0 = *(const bf16x8*)&QKV[rowQA + kgrp * 8];
  const bf16x8 qfA1 = *(const bf16x8*)&QKV[rowQA + 32 + kgrp * 8];
  const bf16x8 qfB0 = *(const bf16x8*)&QKV[rowQB + kgrp * 8];
  const bf16x8 qfB1 = *(const bf16x8*)&QKV[rowQB + 32 + kgrp * 8];

  f32x4 accA[4] = {}, accB[4] = {};  // O^T: row=d=(df*16 + kgrp*4 + j), col=q=rsel
  float mA = -INFINITY, lA = 0.0f, mB = -INFINITY, lB = 0.0f;

  auto vs3 = (__attribute__((address_space(3))) unsigned short*)&Vs[0][0];
  const unsigned vbase0 = (unsigned)(uintptr_t)vs3 + (unsigned)lane * 8u;
  constexpr float SCL = 0.18033688011112042f;  // log2(e)/sqrt(64)

  auto stage = [&](int kt, int b) {
    const int kb = kt * 64;
#pragma unroll
    for (int r = 0; r < 2; ++r) {
      int c = r * 256 + tid;
      int key = c >> 3;
      int dcs = (c & 7) ^ (key & 7);
      GLOAD_LDS16(QKV + (size_t)(bb * Sz + kb + key) * 3072 + 1024 + hh * 64 + dcs * 8,
                  &Kt[b][c * 8]);
    }
#pragma unroll
    for (int r = 0; r < 2; ++r) {
      int c = r * 256 + tid;
      int key = ((c >> 3) & 15) * 4 + ((c >> 1) & 3);
      int d = (c >> 7) * 16 + (c & 1) * 8;
      GLOAD_LDS16(QKV + (size_t)(bb * Sz + kb + key) * 3072 + 2048 + hh * 64 + d,
                  &Vs[b][c * 8]);
    }
  };

  // S^T + online softmax (log2 domain, defer-rescale) -> P^T bf16 B-frags
  auto proc = [&](const unsigned short* Kb, const bf16x8& qf0, const bf16x8& qf1,
                  float& mrun, float& lrun, f32x4* accO, s16x4* pb, bool edge, int qg, int kb) {
    f32x4 sc[4];
    __builtin_amdgcn_s_setprio(1);
#pragma unroll
    for (int kf = 0; kf < 4; ++kf) {
      int key = kf * 16 + rsel;
      bf16x8 k0 = *(const bf16x8*)&Kb[key * 64 + ((kgrp ^ (key & 7)) * 8)];
      bf16x8 k1 = *(const bf16x8*)&Kb[key * 64 + (((4 + kgrp) ^ (key & 7)) * 8)];
      f32x4 s = {};
      s = mfma32(k0, qf0, s);
      s = mfma32(k1, qf1, s);
      sc[kf] = s;
    }
    __builtin_amdgcn_s_setprio(0);
    float tmax = -INFINITY;
#pragma unroll
    for (int kf = 0; kf < 4; ++kf)
#pragma unroll
      for (int j = 0; j < 4; ++j) {
        float v = sc[kf][j] * SCL;
        if (edge) {
          int keyg = kb + kf * 16 + kgrp * 4 + j;
          if (keyg > qg) v = -INFINITY;
        }
        sc[kf][j] = v;
        tmax = fmaxf(tmax, v);
      }
    tmax = fmaxf(tmax, __shfl_xor(tmax, 16));
    tmax = fmaxf(tmax, __shfl_xor(tmax, 32));
    // defer-rescale (T13): only rescale when the running max grows by >8 ulp2
    if (!__all(tmax <= mrun + 8.0f)) {
      const float mnew = fmaxf(mrun, tmax);
      const float corr = exp2f(mrun - mnew);
      lrun *= corr;
#pragma unroll
      for (int df = 0; df < 4; ++df) accO[df] *= corr;
      mrun = mnew;
    }
    float psum = 0.0f;
#pragma unroll
    for (int kf = 0; kf < 4; ++kf) {
      bf16x4 pv;
#pragma unroll
      for (int j = 0; j < 4; ++j) {
        float e = exp2f(sc[kf][j] - mrun);
        psum += e;
        pv[j] = (__bf16)e;  // compiler emits v_cvt_pk_bf16_f32 pairs
      }
      pb[kf] = __builtin_bit_cast(s16x4, pv);
    }
    psum += __shfl_xor(psum, 16);
    psum += __shfl_xor(psum, 32);
    lrun += psum;
  };

  stage(0, 0);
  asm volatile("s_waitcnt vmcnt(0)" ::: "memory");
  __syncthreads();

  for (int kt = 0; kt <= qtB; ++kt) {
    const int kb = kt * 64;
    const int cur = kt & 1;
    const bool doA = (kt <= qtA);
    if (kt < qtB) stage(kt + 1, cur ^ 1);  // issue next-tile loads BEFORE compute

    s16x4 pbA[4], pbB[4];
    if (doA) proc(Kt[cur], qfA0, qfA1, mA, lA, accA, pbA, kt == qtA, qgA, kb);
    proc(Kt[cur], qfB0, qfB1, mB, lB, accB, pbB, kt == qtB, qgB, kb);

    // O^T += V^T @ P^T — V-frags shared by both q-sets
    const unsigned vb = vbase0 + (unsigned)cur * 8192u;
#pragma unroll
    for (int df = 0; df < 4; ++df) {
      unsigned a = vb + df * 2048;
      s16x4 vf0 = tr16<0>(a);
      s16x4 vf1 = tr16<512>(a);
      s16x4 vf2 = tr16<1024>(a);
      s16x4 vf3 = tr16<1536>(a);
      asm volatile("s_waitcnt lgkmcnt(0)" ::: "memory");
      __builtin_amdgcn_sched_barrier(0);
      __builtin_amdgcn_s_setprio(1);
      if (doA) {
        accA[df] = mfma16(vf0, pbA[0], accA[df]);
        accA[df] = mfma16(vf1, pbA[1], accA[df]);
        accA[df] = mfma16(vf2, pbA[2], accA[df]);
        accA[df] = mfma16(vf3, pbA[3], accA[df]);
      }
      accB[df] = mfma16(vf0, pbB[0], accB[df]);
      accB[df] = mfma16(vf1, pbB[1], accB[df]);
      accB[df] = mfma16(vf2, pbB[2], accB[df]);
      accB[df] = mfma16(vf3, pbB[3], accB[df]);
      __builtin_amdgcn_s_setprio(0);
    }

    if (kt < qtB) {
      asm volatile("s_waitcnt vmcnt(0)" ::: "memory");  // next tile's LDS landed
      __syncthreads();
    }
  }

  auto epi = [&](const f32x4* accO, float lrun, int qg) {
    const float rl = 1.0f / lrun;
    const size_t orow = (size_t)(bb * Sz + qg) * Dz + hh * 64;
#pragma unroll
    for (int df = 0; df < 4; ++df) {
      s16x4 o;
#pragma unroll
      for (int j = 0; j < 4; ++j) o[j] = (short)f2bu(accO[df][j] * rl);
      *(s16x4*)&outA[orow + df * 16 + kgrp * 4] = o;
    }
  };
  epi(accA, lA, qgA);
  epi(accB, lB, qgB);
}

// ---------------- launch ----------------

extern "C" void kernel_launch(void* const* d_in, const int* in_sizes, int n_in,
                              void* d_out, int out_size, void* d_ws, size_t ws_size,
                              hipStream_t stream) {
  const float* x   = (const float*)d_in[0];
  // d_in[1] = mask (causal, known) — unused
  const float* wq  = (const float*)d_in[2];
  const float* wk  = (const float*)d_in[3];
  const float* wv  = (const float*)d_in[4];
  const float* wo  = (const float*)d_in[5];
  const float* w1  = (const float*)d_in[6];
  const float* b1  = (const float*)d_in[7];
  const float* w2  = (const float*)d_in[8];
  const float* b2  = (const float*)d_in[9];
  const float* g1  = (const float*)d_in[10];
  const float* be1 = (const float*)d_in[11];
  const float* g2  = (const float*)d_in[12];
  const float* be2 = (const float*)d_in[13];
  float* out = (float*)d_out;

  char* ws = (char*)d_ws;
  unsigned short* WqkvT = (unsigned short*)(ws);
  unsigned short* WoT   = (unsigned short*)(ws + 6291456);
  unsigned short* W1T   = (unsigned short*)(ws + 8388608);
  unsigned short* W2T   = (unsigned short*)(ws + 16777216);
  unsigned short* hbuf  = (unsigned short*)(ws + 25165824);
  unsigned short* big   = (unsigned short*)(ws + 41943040);  // QKV, later ff1

  dim3 tb(32, 8);
  pack_qkv<<<768, 256, 0, stream>>>(wq, wk, wv, WqkvT);
  transpose_f32_to_bf16<<<dim3(32, 32), tb, 0, stream>>>(wo, WoT, 1024, 1024);
  transpose_f32_to_bf16<<<dim3(128, 32), tb, 0, stream>>>(w1, W1T, 1024, 4096);
  transpose_f32_to_bf16<<<dim3(32, 128), tb, 0, stream>>>(w2, W2T, 4096, 1024);

  ln_kernel<<<Mz, 256, 0, stream>>>(x, g1, be1, hbuf);
  gemm_kernel<EPI_BF16><<<dim3(24, 64), 256, 0, stream>>>(
      hbuf, WqkvT, Mz, 3072, 1024, nullptr, nullptr, big, nullptr);
  attn_kernel<<<1024, 256, 0, stream>>>(big, hbuf);
  gemm_kernel<EPI_RES_F32><<<dim3(8, 64), 256, 0, stream>>>(
      hbuf, WoT, Mz, 1024, 1024, nullptr, x, nullptr, out);
  ln_kernel<<<Mz, 256, 0, stream>>>(out, g2, be2, hbuf);
  gemm_kernel<EPI_GELU_BF16><<<dim3(32, 64), 256, 0, stream>>>(
      hbuf, W1T, Mz, Fz, 1024, b1, nullptr, big, nullptr);
  gemm_kernel<EPI_BIAS_RES_F32><<<dim3(8, 64), 256, 0, stream>>>(
      big, W2T, Mz, 1024, Fz, b2, out, nullptr, out);
}

// Round 4
// 499.795 us; speedup vs baseline: 1.0962x; 1.0962x over previous
//
#include <hip/hip_runtime.h>
#include <hip/hip_bf16.h>
#include <math.h>

// GPT decoder layer, MI355X/gfx950. bf16 MFMA GEMMs + fused flash attention.
// B=4 S=2048 D=1024 H=16 DH=64 F=4096.  Workspace layout (bytes):
//   [0,6M)      WqkvT  bf16 [3072][1024]   (pre-transposed, k-contiguous)
//   [6M,8M)     WoT    bf16 [1024][1024]
//   [8M,16M)    W1T    bf16 [4096][1024]
//   [16M,24M)   W2T    bf16 [1024][4096]
//   [24M,40M)   hbuf   bf16 [8192][1024]   (h -> attn_out -> h2, reused)
//   [40M,104M)  big    bf16                (QKV [8192][3072], later ff1 [8192][4096])

#define Bz 4
#define Sz 2048
#define Dz 1024
#define Hz 16
#define DHz 64
#define Fz 4096
#define Mz 8192

typedef float f32x4 __attribute__((ext_vector_type(4)));
typedef __bf16 bf16x8 __attribute__((ext_vector_type(8)));
typedef __bf16 bf16x4 __attribute__((ext_vector_type(4)));
typedef short s16x4 __attribute__((ext_vector_type(4)));

#define GLOAD_LDS16(g, l)                                                                   \
  __builtin_amdgcn_global_load_lds((const __attribute__((address_space(1))) unsigned int*)(g), \
                                   (__attribute__((address_space(3))) unsigned int*)(l), 16, 0, 0)

static __device__ __forceinline__ unsigned short f2bu(float f) {
  unsigned int u = __float_as_uint(f);
  u += 0x7fffu + ((u >> 16) & 1u);   // RNE to bf16
  return (unsigned short)(u >> 16);
}

static __device__ __forceinline__ f32x4 mfma32(bf16x8 a, bf16x8 b, f32x4 c) {
  return __builtin_amdgcn_mfma_f32_16x16x32_bf16(a, b, c, 0, 0, 0);
}
static __device__ __forceinline__ f32x4 mfma16(s16x4 a, s16x4 b, f32x4 c) {
#if __has_builtin(__builtin_amdgcn_mfma_f32_16x16x16bf16_1k)
  return __builtin_amdgcn_mfma_f32_16x16x16bf16_1k(a, b, c, 0, 0, 0);
#else
  asm("v_mfma_f32_16x16x16_bf16 %0, %1, %2, %0" : "+v"(c) : "v"(a), "v"(b));
  return c;
#endif
}

// hardware transpose read: lane l elem j <- lds[base + (l&15) + j*16 + (l>>4)*64] (bf16 elems)
template <int OFF>
static __device__ __forceinline__ s16x4 tr16(unsigned addr) {
  s16x4 r;
  asm volatile("ds_read_b64_tr_b16 %0, %1 offset:%2" : "=v"(r) : "v"(addr), "i"(OFF));
  return r;
}

// ---------------- weight packing ----------------

__global__ __launch_bounds__(256) void pack_qkv(
    const float* __restrict__ wq, const float* __restrict__ wk, const float* __restrict__ wv,
    unsigned short* __restrict__ outW)  // [3072][1024], row n = proj*1024 + h*64 + e, col = d
{
  __shared__ float tile[64][65];
  const int blk = blockIdx.x;       // 768 = 16 dchunk x 16 h x 3 proj
  const int dc = blk & 15;
  const int h  = (blk >> 4) & 15;
  const int p  = blk >> 8;
  const float* w = p == 0 ? wq : (p == 1 ? wk : wv);
  const int tid = threadIdx.x;
#pragma unroll
  for (int i = 0; i < 4; ++i) {
    int idx = i * 256 + tid;
    int dl = idx >> 4;
    int e0 = (idx & 15) * 4;
    const float4 v = *(const float4*)&w[(size_t)(h * 1024 + dc * 64 + dl) * 64 + e0];
    tile[dl][e0 + 0] = v.x; tile[dl][e0 + 1] = v.y;
    tile[dl][e0 + 2] = v.z; tile[dl][e0 + 3] = v.w;
  }
  __syncthreads();
#pragma unroll
  for (int i = 0; i < 4; ++i) {
    int idx = i * 256 + tid;
    int e = idx >> 4;
    int d0 = (idx & 15) * 4;
    ushort4 o;
    o.x = f2bu(tile[d0 + 0][e]); o.y = f2bu(tile[d0 + 1][e]);
    o.z = f2bu(tile[d0 + 2][e]); o.w = f2bu(tile[d0 + 3][e]);
    *(ushort4*)&outW[(size_t)(p * 1024 + h * 64 + e) * 1024 + dc * 64 + d0] = o;
  }
}

__global__ __launch_bounds__(256) void transpose_f32_to_bf16(
    const float* __restrict__ in, unsigned short* __restrict__ out, int R, int C)
{ // in [R][C] fp32 -> out [C][R] bf16
  __shared__ float tile[32][33];
  int c0 = blockIdx.x * 32, r0 = blockIdx.y * 32;
  int x = threadIdx.x, y = threadIdx.y;
#pragma unroll
  for (int i = 0; i < 32; i += 8)
    tile[y + i][x] = in[(size_t)(r0 + y + i) * C + c0 + x];
  __syncthreads();
#pragma unroll
  for (int i = 0; i < 32; i += 8)
    out[(size_t)(c0 + y + i) * R + r0 + x] = f2bu(tile[x][y + i]);
}

// ---------------- layernorm ----------------

__global__ __launch_bounds__(256) void ln_kernel(
    const float* __restrict__ x, const float* __restrict__ gamma, const float* __restrict__ beta,
    unsigned short* __restrict__ outH)
{
  const int row = blockIdx.x;
  const int tid = threadIdx.x;
  const float4 v = ((const float4*)(x + (size_t)row * Dz))[tid];
  float s = v.x + v.y + v.z + v.w;
  float s2 = v.x * v.x + v.y * v.y + v.z * v.z + v.w * v.w;
#pragma unroll
  for (int o = 32; o > 0; o >>= 1) {
    s += __shfl_xor(s, o);
    s2 += __shfl_xor(s2, o);
  }
  __shared__ float ss[4], ss2[4];
  if ((tid & 63) == 0) { ss[tid >> 6] = s; ss2[tid >> 6] = s2; }
  __syncthreads();
  s = ss[0] + ss[1] + ss[2] + ss[3];
  s2 = ss2[0] + ss2[1] + ss2[2] + ss2[3];
  const float mean = s * (1.0f / Dz);
  const float rstd = rsqrtf(s2 * (1.0f / Dz) - mean * mean + 1e-5f);
  const float4 g4 = ((const float4*)gamma)[tid];
  const float4 b4 = ((const float4*)beta)[tid];
  ushort4 o;
  o.x = f2bu((v.x - mean) * rstd * g4.x + b4.x);
  o.y = f2bu((v.y - mean) * rstd * g4.y + b4.y);
  o.z = f2bu((v.z - mean) * rstd * g4.z + b4.z);
  o.w = f2bu((v.w - mean) * rstd * g4.w + b4.w);
  ((ushort4*)(outH + (size_t)row * Dz))[tid] = o;
}

// ---------------- GEMM 256xBN, BK=64, 8 waves (2Mx4N), counted-vmcnt dbuf ----------------
// C[M,N] = A[M,K](bf16) @ BT[N,K]^T(bf16). Pipeline per K-tile t:
//   issue(t+1) -> s_waitcnt vmcnt(NCH) [t's chunks landed; t+1 stays in flight]
//   -> raw s_barrier -> compute(t) -> raw s_barrier [protects buf (t+2) will overwrite].
// NEVER __syncthreads() in the loop (it drains vmcnt(0) = the m97 stall).
// LDS 16B chunks XOR-swizzled by row&7 (pre-swizzled global source, linear LDS dest;
// read applies the same involution) -> ds_read_b128 is 2-way-conflict max (free).

enum { EPI_BF16 = 0, EPI_GELU_BF16 = 1, EPI_RES_F32 = 2, EPI_BIAS_RES_F32 = 3 };

template <int BN, int EPI>
__global__ __launch_bounds__(512, 2) void gemm256(
    const unsigned short* __restrict__ A,   // [M,K] bf16
    const unsigned short* __restrict__ BT,  // [N,K] bf16
    int M, int N, int K,
    const float* bias, const float* resid,  // resid/outf may alias: no __restrict__
    unsigned short* outb, float* outf)
{
  constexpr int BM = 256, BK = 64;
  constexpr int ACH = (BM * BK * 2) / (512 * 16);  // 4 gload chunks per K-tile (A)
  constexpr int BCH = (BN * BK * 2) / (512 * 16);  // 4 (BN=256) or 2 (BN=128)
  constexpr int NCH = ACH + BCH;                   // 8 or 6
  constexpr int NREP = BN / 64;                    // wave N-frags: 4 or 2
  __shared__ unsigned short As[2][BM * BK];
  __shared__ unsigned short Bs[2][BN * BK];

  const int tid = threadIdx.x;
  const int lane = tid & 63;
  const int wid = tid >> 6;
  const int wr = wid >> 2;        // 2 wave-rows of 128
  const int wc = wid & 3;         // 4 wave-cols of BN/4
  const int rsel = lane & 15;
  const int kgrp = lane >> 4;

  // XCD-chunked bijective swizzle (nwg % 8 == 0 for all our grids)
  const int nwg = gridDim.x;
  const int bid = blockIdx.x;
  const int id2 = (bid & 7) * (nwg >> 3) + (bid >> 3);
  const int nbx = N / BN;
  const int n0 = (id2 % nbx) * BN;
  const int m0 = (id2 / nbx) * BM;

  f32x4 acc[8][NREP] = {};

  auto issue = [&](int kt, int b) {
    const int kOff = kt * BK;
#pragma unroll
    for (int r = 0; r < ACH; ++r) {
      int gc = r * 512 + tid;
      int row = gc >> 3;
      int kcs = (gc & 7) ^ (row & 7);
      GLOAD_LDS16(A + (size_t)(m0 + row) * K + kOff + kcs * 8, &As[b][gc * 8]);
    }
#pragma unroll
    for (int r = 0; r < BCH; ++r) {
      int gc = r * 512 + tid;
      int row = gc >> 3;
      int kcs = (gc & 7) ^ (row & 7);
      GLOAD_LDS16(BT + (size_t)(n0 + row) * K + kOff + kcs * 8, &Bs[b][gc * 8]);
    }
  };

  auto compute = [&](int b) {
    const unsigned short* Ab = As[b];
    const unsigned short* Bb = Bs[b];
#pragma unroll
    for (int kk = 0; kk < 2; ++kk) {
      bf16x8 af[8], bfr[NREP];
#pragma unroll
      for (int mf = 0; mf < 8; ++mf) {
        int ar = wr * 128 + mf * 16 + rsel;
        af[mf] = *(const bf16x8*)&Ab[ar * 64 + (((kk * 4 + kgrp) ^ (ar & 7)) * 8)];
      }
#pragma unroll
      for (int nf = 0; nf < NREP; ++nf) {
        int br = wc * (BN / 4) + nf * 16 + rsel;
        bfr[nf] = *(const bf16x8*)&Bb[br * 64 + (((kk * 4 + kgrp) ^ (br & 7)) * 8)];
      }
#pragma unroll
      for (int mf = 0; mf < 8; ++mf)
#pragma unroll
        for (int nf = 0; nf < NREP; ++nf)
          acc[mf][nf] = mfma32(af[mf], bfr[nf], acc[mf][nf]);
    }
  };

  const int T = K >> 6;
  issue(0, 0);
  for (int t = 0; t < T; ++t) {
    if (t + 1 < T) {
      issue(t + 1, (t + 1) & 1);  // buf last read in compute(t-1), sealed by end-of-(t-1) barrier
      if constexpr (NCH == 8) asm volatile("s_waitcnt vmcnt(8)" ::: "memory");
      else                    asm volatile("s_waitcnt vmcnt(6)" ::: "memory");
    } else {
      asm volatile("s_waitcnt vmcnt(0)" ::: "memory");
    }
    __builtin_amdgcn_sched_barrier(0);
    __builtin_amdgcn_s_barrier();   // all waves' tile-t chunks landed
    __builtin_amdgcn_sched_barrier(0);
    compute(t & 1);
    __builtin_amdgcn_sched_barrier(0);
    __builtin_amdgcn_s_barrier();   // all waves done reading buf[t&1] before t+1 overwrites it
  }

#pragma unroll
  for (int mf = 0; mf < 8; ++mf) {
#pragma unroll
    for (int nf = 0; nf < NREP; ++nf) {
      const int n = n0 + wc * (BN / 4) + nf * 16 + rsel;
#pragma unroll
      for (int j = 0; j < 4; ++j) {
        const int m = m0 + wr * 128 + mf * 16 + kgrp * 4 + j;
        const size_t idx = (size_t)m * N + n;
        float v = acc[mf][nf][j];
        if constexpr (EPI == EPI_BF16) {
          outb[idx] = f2bu(v);
        } else if constexpr (EPI == EPI_GELU_BF16) {
          v += bias[n];
          v = 0.5f * v * (1.0f + erff(v * 0.70710678118654752f));
          outb[idx] = f2bu(v);
        } else if constexpr (EPI == EPI_RES_F32) {
          outf[idx] = v + resid[idx];
        } else {
          outf[idx] = v + bias[n] + resid[idx];
        }
      }
    }
  }
}

// ---------------- fused causal flash attention (R2 structure) ----------------
// Block = pair of q-tiles {pi, 31-pi} x head x batch: 33 compute-tiles per block,
// pair shares K/V staging. 3D grid (round-robin XCD — measured better than grouping).
// S^T = K @ Q^T via mfma 16x16x32; P^T stays in registers as the B-frag of
// mfma 16x16x16 for O^T = V^T @ P^T; V read with ds_read_b64_tr_b16.
// Softmax in log2 domain with defer-rescale (THR=8) and packed bf16 cvt.

__global__ __launch_bounds__(256, 4) void attn_kernel(
    const unsigned short* __restrict__ QKV,  // [Mz][3072] bf16 (q|k|v, feature h*64+e)
    unsigned short* __restrict__ outA)       // [Mz][Dz]  bf16
{
  __shared__ unsigned short Kt[64 * 64];  // [key][d], 16B d-chunk XOR-swizzled by key&7
  __shared__ unsigned short Vs[64 * 64];  // subtiled for tr16 reads
  const int pi = blockIdx.x;
  const int hh = blockIdx.y;
  const int bb = blockIdx.z;
  const int tid = threadIdx.x;
  const int lane = tid & 63;
  const int w = tid >> 6;
  const int rsel = lane & 15;
  const int kgrp = lane >> 4;
  const int qtA = pi, qtB = 31 - pi;
  const int qgA = qtA * 64 + w * 16 + rsel;
  const int qgB = qtB * 64 + w * 16 + rsel;
  const size_t rowQA = (size_t)(bb * Sz + qgA) * 3072 + hh * 64;
  const size_t rowQB = (size_t)(bb * Sz + qgB) * 3072 + hh * 64;

  const bf16x8 qfA0 = *(const bf16x8*)&QKV[rowQA + kgrp * 8];
  const bf16x8 qfA1 = *(const bf16x8*)&QKV[rowQA + 32 + kgrp * 8];
  const bf16x8 qfB0 = *(const bf16x8*)&QKV[rowQB + kgrp * 8];
  const bf16x8 qfB1 = *(const bf16x8*)&QKV[rowQB + 32 + kgrp * 8];

  f32x4 accA[4] = {}, accB[4] = {};  // O^T: row=d=(df*16 + kgrp*4 + j), col=q=rsel
  float mA = -INFINITY, lA = 0.0f, mB = -INFINITY, lB = 0.0f;

  auto vs3 = (__attribute__((address_space(3))) unsigned short*)Vs;
  const unsigned vbase = (unsigned)(uintptr_t)vs3 + (unsigned)lane * 8u;
  constexpr float SCL = 0.18033688011112042f;  // log2(e)/sqrt(64)

  // S^T + online softmax (log2 domain, defer-rescale) -> P^T bf16 B-frags
  auto proc = [&](const bf16x8& qf0, const bf16x8& qf1, float& mrun, float& lrun,
                  f32x4* accO, s16x4* pb, bool edge, int qg, int kb) {
    f32x4 sc[4];
    __builtin_amdgcn_s_setprio(1);
#pragma unroll
    for (int kf = 0; kf < 4; ++kf) {
      int key = kf * 16 + rsel;
      bf16x8 k0 = *(const bf16x8*)&Kt[key * 64 + ((kgrp ^ (key & 7)) * 8)];
      bf16x8 k1 = *(const bf16x8*)&Kt[key * 64 + (((4 + kgrp) ^ (key & 7)) * 8)];
      f32x4 s = {};
      s = mfma32(k0, qf0, s);
      s = mfma32(k1, qf1, s);
      sc[kf] = s;
    }
    __builtin_amdgcn_s_setprio(0);
    float tmax = -INFINITY;
#pragma unroll
    for (int kf = 0; kf < 4; ++kf)
#pragma unroll
      for (int j = 0; j < 4; ++j) {
        float v = sc[kf][j] * SCL;
        if (edge) {
          int keyg = kb + kf * 16 + kgrp * 4 + j;
          if (keyg > qg) v = -INFINITY;
        }
        sc[kf][j] = v;
        tmax = fmaxf(tmax, v);
      }
    tmax = fmaxf(tmax, __shfl_xor(tmax, 16));
    tmax = fmaxf(tmax, __shfl_xor(tmax, 32));
    // defer-rescale (T13): skip O/l rescale while max growth stays under 8 (log2 units)
    if (!__all(tmax <= mrun + 8.0f)) {
      const float mnew = fmaxf(mrun, tmax);
      const float corr = exp2f(mrun - mnew);
      lrun *= corr;
#pragma unroll
      for (int df = 0; df < 4; ++df) accO[df] *= corr;
      mrun = mnew;
    }
    float psum = 0.0f;
#pragma unroll
    for (int kf = 0; kf < 4; ++kf) {
      bf16x4 pv;
#pragma unroll
      for (int j = 0; j < 4; ++j) {
        float e = exp2f(sc[kf][j] - mrun);
        psum += e;
        pv[j] = (__bf16)e;  // v_cvt_pk_bf16_f32 pairs
      }
      pb[kf] = __builtin_bit_cast(s16x4, pv);
    }
    psum += __shfl_xor(psum, 16);
    psum += __shfl_xor(psum, 32);
    lrun += psum;
  };

  for (int kt = 0; kt <= qtB; ++kt) {
    const int kb = kt * 64;
    const bool doA = (kt <= qtA);
    if (kt) __syncthreads();  // prev tile's LDS reads done before overwrite
    // stage K: LDS linear, global d-chunk XOR-swizzled by key&7
#pragma unroll
    for (int r = 0; r < 2; ++r) {
      int c = r * 256 + tid;
      int key = c >> 3;
      int dcs = (c & 7) ^ (key & 7);
      GLOAD_LDS16(QKV + (size_t)(bb * Sz + kb + key) * 3072 + 1024 + hh * 64 + dcs * 8,
                  &Kt[c * 8]);
    }
    // stage V: LDS linear; source permuted so LDS holds subtiled layout
#pragma unroll
    for (int r = 0; r < 2; ++r) {
      int c = r * 256 + tid;
      int key = ((c >> 3) & 15) * 4 + ((c >> 1) & 3);
      int d = (c >> 7) * 16 + (c & 1) * 8;
      GLOAD_LDS16(QKV + (size_t)(bb * Sz + kb + key) * 3072 + 2048 + hh * 64 + d,
                  &Vs[c * 8]);
    }
    __syncthreads();

    s16x4 pbA[4], pbB[4];
    if (doA) proc(qfA0, qfA1, mA, lA, accA, pbA, kt == qtA, qgA, kb);
    proc(qfB0, qfB1, mB, lB, accB, pbB, kt == qtB, qgB, kb);

    // O^T += V^T @ P^T — V-frags shared by both q-sets
#pragma unroll
    for (int df = 0; df < 4; ++df) {
      unsigned a = vbase + df * 2048;
      s16x4 vf0 = tr16<0>(a);
      s16x4 vf1 = tr16<512>(a);
      s16x4 vf2 = tr16<1024>(a);
      s16x4 vf3 = tr16<1536>(a);
      asm volatile("s_waitcnt lgkmcnt(0)" ::: "memory");
      __builtin_amdgcn_sched_barrier(0);
      __builtin_amdgcn_s_setprio(1);
      if (doA) {
        accA[df] = mfma16(vf0, pbA[0], accA[df]);
        accA[df] = mfma16(vf1, pbA[1], accA[df]);
        accA[df] = mfma16(vf2, pbA[2], accA[df]);
        accA[df] = mfma16(vf3, pbA[3], accA[df]);
      }
      accB[df] = mfma16(vf0, pbB[0], accB[df]);
      accB[df] = mfma16(vf1, pbB[1], accB[df]);
      accB[df] = mfma16(vf2, pbB[2], accB[df]);
      accB[df] = mfma16(vf3, pbB[3], accB[df]);
      __builtin_amdgcn_s_setprio(0);
    }
  }

  auto epi = [&](const f32x4* accO, float lrun, int qg) {
    const float rl = 1.0f / lrun;
    const size_t orow = (size_t)(bb * Sz + qg) * Dz + hh * 64;
#pragma unroll
    for (int df = 0; df < 4; ++df) {
      s16x4 o;
#pragma unroll
      for (int j = 0; j < 4; ++j) o[j] = (short)f2bu(accO[df][j] * rl);
      *(s16x4*)&outA[orow + df * 16 + kgrp * 4] = o;
    }
  };
  epi(accA, lA, qgA);
  epi(accB, lB, qgB);
}

// ---------------- launch ----------------

extern "C" void kernel_launch(void* const* d_in, const int* in_sizes, int n_in,
                              void* d_out, int out_size, void* d_ws, size_t ws_size,
                              hipStream_t stream) {
  const float* x   = (const float*)d_in[0];
  // d_in[1] = mask (causal, known) — unused
  const float* wq  = (const float*)d_in[2];
  const float* wk  = (const float*)d_in[3];
  const float* wv  = (const float*)d_in[4];
  const float* wo  = (const float*)d_in[5];
  const float* w1  = (const float*)d_in[6];
  const float* b1  = (const float*)d_in[7];
  const float* w2  = (const float*)d_in[8];
  const float* b2  = (const float*)d_in[9];
  const float* g1  = (const float*)d_in[10];
  const float* be1 = (const float*)d_in[11];
  const float* g2  = (const float*)d_in[12];
  const float* be2 = (const float*)d_in[13];
  float* out = (float*)d_out;

  char* ws = (char*)d_ws;
  unsigned short* WqkvT = (unsigned short*)(ws);
  unsigned short* WoT   = (unsigned short*)(ws + 6291456);
  unsigned short* W1T   = (unsigned short*)(ws + 8388608);
  unsigned short* W2T   = (unsigned short*)(ws + 16777216);
  unsigned short* hbuf  = (unsigned short*)(ws + 25165824);
  unsigned short* big   = (unsigned short*)(ws + 41943040);  // QKV, later ff1

  dim3 tb(32, 8);
  pack_qkv<<<768, 256, 0, stream>>>(wq, wk, wv, WqkvT);
  transpose_f32_to_bf16<<<dim3(32, 32), tb, 0, stream>>>(wo, WoT, 1024, 1024);
  transpose_f32_to_bf16<<<dim3(128, 32), tb, 0, stream>>>(w1, W1T, 1024, 4096);
  transpose_f32_to_bf16<<<dim3(32, 128), tb, 0, stream>>>(w2, W2T, 4096, 1024);

  ln_kernel<<<Mz, 256, 0, stream>>>(x, g1, be1, hbuf);
  gemm256<256, EPI_BF16><<<384, 512, 0, stream>>>(
      hbuf, WqkvT, Mz, 3072, 1024, nullptr, nullptr, big, nullptr);
  attn_kernel<<<dim3(16, 16, 4), 256, 0, stream>>>(big, hbuf);
  gemm256<128, EPI_RES_F32><<<256, 512, 0, stream>>>(
      hbuf, WoT, Mz, 1024, 1024, nullptr, x, nullptr, out);
  ln_kernel<<<Mz, 256, 0, stream>>>(out, g2, be2, hbuf);
  gemm256<256, EPI_GELU_BF16><<<512, 512, 0, stream>>>(
      hbuf, W1T, Mz, Fz, 1024, b1, nullptr, big, nullptr);
  gemm256<128, EPI_BIAS_RES_F32><<<256, 512, 0, stream>>>(
      big, W2T, Mz, 1024, Fz, b2, out, nullptr, out);
}

// Round 5
// 459.931 us; speedup vs baseline: 1.1912x; 1.0867x over previous
//
#include <hip/hip_runtime.h>
#include <hip/hip_bf16.h>
#include <math.h>

// GPT decoder layer, MI355X/gfx950. bf16 MFMA GEMMs + fused flash attention.
// B=4 S=2048 D=1024 H=16 DH=64 F=4096.  Workspace layout (bytes):
//   [0,6M)      WqkvT  bf16 [3072][1024]   (pre-transposed, k-contiguous)
//   [6M,8M)     WoT    bf16 [1024][1024]
//   [8M,16M)    W1T    bf16 [4096][1024]
//   [16M,24M)   W2T    bf16 [1024][4096]
//   [24M,40M)   hbuf   bf16 [8192][1024]   (h -> attn_out -> h2, reused)
//   [40M,104M)  big    bf16                (QKV [8192][3072], later ff1 [8192][4096])

#define Bz 4
#define Sz 2048
#define Dz 1024
#define Hz 16
#define DHz 64
#define Fz 4096
#define Mz 8192

typedef float f32x4 __attribute__((ext_vector_type(4)));
typedef __bf16 bf16x8 __attribute__((ext_vector_type(8)));
typedef __bf16 bf16x4 __attribute__((ext_vector_type(4)));
typedef short s16x4 __attribute__((ext_vector_type(4)));

#define GLOAD_LDS16(g, l)                                                                   \
  __builtin_amdgcn_global_load_lds((const __attribute__((address_space(1))) unsigned int*)(g), \
                                   (__attribute__((address_space(3))) unsigned int*)(l), 16, 0, 0)

static __device__ __forceinline__ unsigned short f2bu(float f) {
  unsigned int u = __float_as_uint(f);
  u += 0x7fffu + ((u >> 16) & 1u);   // RNE to bf16
  return (unsigned short)(u >> 16);
}

static __device__ __forceinline__ f32x4 mfma32(bf16x8 a, bf16x8 b, f32x4 c) {
  return __builtin_amdgcn_mfma_f32_16x16x32_bf16(a, b, c, 0, 0, 0);
}
static __device__ __forceinline__ f32x4 mfma16(s16x4 a, s16x4 b, f32x4 c) {
#if __has_builtin(__builtin_amdgcn_mfma_f32_16x16x16bf16_1k)
  return __builtin_amdgcn_mfma_f32_16x16x16bf16_1k(a, b, c, 0, 0, 0);
#else
  asm("v_mfma_f32_16x16x16_bf16 %0, %1, %2, %0" : "+v"(c) : "v"(a), "v"(b));
  return c;
#endif
}

// hardware transpose read: lane l elem j <- lds[base + (l&15) + j*16 + (l>>4)*64] (bf16 elems)
template <int OFF>
static __device__ __forceinline__ s16x4 tr16(unsigned addr) {
  s16x4 r;
  asm volatile("ds_read_b64_tr_b16 %0, %1 offset:%2" : "=v"(r) : "v"(addr), "i"(OFF));
  return r;
}

// ---------------- weight packing ----------------

__global__ __launch_bounds__(256) void pack_qkv(
    const float* __restrict__ wq, const float* __restrict__ wk, const float* __restrict__ wv,
    unsigned short* __restrict__ outW)  // [3072][1024], row n = proj*1024 + h*64 + e, col = d
{
  __shared__ float tile[64][65];
  const int blk = blockIdx.x;       // 768 = 16 dchunk x 16 h x 3 proj
  const int dc = blk & 15;
  const int h  = (blk >> 4) & 15;
  const int p  = blk >> 8;
  const float* w = p == 0 ? wq : (p == 1 ? wk : wv);
  const int tid = threadIdx.x;
#pragma unroll
  for (int i = 0; i < 4; ++i) {
    int idx = i * 256 + tid;
    int dl = idx >> 4;
    int e0 = (idx & 15) * 4;
    const float4 v = *(const float4*)&w[(size_t)(h * 1024 + dc * 64 + dl) * 64 + e0];
    tile[dl][e0 + 0] = v.x; tile[dl][e0 + 1] = v.y;
    tile[dl][e0 + 2] = v.z; tile[dl][e0 + 3] = v.w;
  }
  __syncthreads();
#pragma unroll
  for (int i = 0; i < 4; ++i) {
    int idx = i * 256 + tid;
    int e = idx >> 4;
    int d0 = (idx & 15) * 4;
    ushort4 o;
    o.x = f2bu(tile[d0 + 0][e]); o.y = f2bu(tile[d0 + 1][e]);
    o.z = f2bu(tile[d0 + 2][e]); o.w = f2bu(tile[d0 + 3][e]);
    *(ushort4*)&outW[(size_t)(p * 1024 + h * 64 + e) * 1024 + dc * 64 + d0] = o;
  }
}

__global__ __launch_bounds__(256) void transpose_f32_to_bf16(
    const float* __restrict__ in, unsigned short* __restrict__ out, int R, int C)
{ // in [R][C] fp32 -> out [C][R] bf16
  __shared__ float tile[32][33];
  int c0 = blockIdx.x * 32, r0 = blockIdx.y * 32;
  int x = threadIdx.x, y = threadIdx.y;
#pragma unroll
  for (int i = 0; i < 32; i += 8)
    tile[y + i][x] = in[(size_t)(r0 + y + i) * C + c0 + x];
  __syncthreads();
#pragma unroll
  for (int i = 0; i < 32; i += 8)
    out[(size_t)(c0 + y + i) * R + r0 + x] = f2bu(tile[x][y + i]);
}

// ---------------- layernorm ----------------

__global__ __launch_bounds__(256) void ln_kernel(
    const float* __restrict__ x, const float* __restrict__ gamma, const float* __restrict__ beta,
    unsigned short* __restrict__ outH)
{
  const int row = blockIdx.x;
  const int tid = threadIdx.x;
  const float4 v = ((const float4*)(x + (size_t)row * Dz))[tid];
  float s = v.x + v.y + v.z + v.w;
  float s2 = v.x * v.x + v.y * v.y + v.z * v.z + v.w * v.w;
#pragma unroll
  for (int o = 32; o > 0; o >>= 1) {
    s += __shfl_xor(s, o);
    s2 += __shfl_xor(s2, o);
  }
  __shared__ float ss[4], ss2[4];
  if ((tid & 63) == 0) { ss[tid >> 6] = s; ss2[tid >> 6] = s2; }
  __syncthreads();
  s = ss[0] + ss[1] + ss[2] + ss[3];
  s2 = ss2[0] + ss2[1] + ss2[2] + ss2[3];
  const float mean = s * (1.0f / Dz);
  const float rstd = rsqrtf(s2 * (1.0f / Dz) - mean * mean + 1e-5f);
  const float4 g4 = ((const float4*)gamma)[tid];
  const float4 b4 = ((const float4*)beta)[tid];
  ushort4 o;
  o.x = f2bu((v.x - mean) * rstd * g4.x + b4.x);
  o.y = f2bu((v.y - mean) * rstd * g4.y + b4.y);
  o.z = f2bu((v.z - mean) * rstd * g4.z + b4.z);
  o.w = f2bu((v.w - mean) * rstd * g4.w + b4.w);
  ((ushort4*)(outH + (size_t)row * Dz))[tid] = o;
}

// ---------------- GEMM 256xBN, BK=64, 8 waves (2Mx4N), 4-phase pipelined ----------------
// C[M,N] = A[M,K](bf16) @ BT[N,K]^T(bf16).
// Per K-tile: 4 phases (kk-half x m-half quadrants). Each phase:
//   ds_read quadrant frags | issue 2 staging chunks of tile t+1 (other buffer ->
//   never conflicts with this tile's reads) | [vmcnt] | barrier | lgkmcnt(0) |
//   setprio(1) + 16 MFMA + setprio(0) | barrier.
// Stage-chunk stream order: B-strips, then A-strips 0,2 (needed by phase 0: rows
// 0-63/128-191), then A-strips 1,3 (phase 1). vmcnt(2) at phases 0 and 3 allows
// exactly the 2 newest (not-yet-needed) chunks to remain in flight (FIFO); the
// last tile (nothing staged after) drains with vmcnt(0). Never vmcnt(0) mid-loop.
// LDS 16B chunks XOR-swizzled by row&7 (pre-swizzled global source, linear dest).

enum { EPI_BF16 = 0, EPI_GELU_BF16 = 1, EPI_RES_F32 = 2, EPI_BIAS_RES_F32 = 3 };

template <int BN, int EPI>
__global__ __launch_bounds__(512, 2) void gemm256(
    const unsigned short* __restrict__ A,   // [M,K] bf16
    const unsigned short* __restrict__ BT,  // [N,K] bf16
    int M, int N, int K,
    const float* bias, const float* resid,  // resid/outf may alias: no __restrict__
    unsigned short* outb, float* outf)
{
  constexpr int BM = 256, BK = 64;
  constexpr int BCH = (BN * BK * 2) / (512 * 16);  // B stage chunks: 4 (BN=256) / 2 (128)
  constexpr int NREP = BN / 64;                    // wave N-frags: 4 or 2
  __shared__ unsigned short As[2][BM * BK];
  __shared__ unsigned short Bs[2][BN * BK];

  const int tid = threadIdx.x;
  const int lane = tid & 63;
  const int wid = tid >> 6;
  const int wr = wid >> 2;        // 2 wave-rows of 128
  const int wc = wid & 3;         // 4 wave-cols of BN/4
  const int rsel = lane & 15;
  const int kgrp = lane >> 4;

  // XCD-chunked bijective swizzle (nwg % 8 == 0 for all our grids)
  const int nwg = gridDim.x;
  const int bid = blockIdx.x;
  const int id2 = (bid & 7) * (nwg >> 3) + (bid >> 3);
  const int nbx = N / BN;
  const int n0 = (id2 % nbx) * BN;
  const int m0 = (id2 / nbx) * BM;

  f32x4 acc[8][NREP] = {};

  auto stA = [&](int kt, int b, int r) {  // A strip r = rows 64r..64r+63
    int gc = r * 512 + tid;
    int row = gc >> 3;
    int kcs = (gc & 7) ^ (row & 7);
    GLOAD_LDS16(A + (size_t)(m0 + row) * K + kt * BK + kcs * 8, &As[b][gc * 8]);
  };
  auto stB = [&](int kt, int b, int r) {
    int gc = r * 512 + tid;
    int row = gc >> 3;
    int kcs = (gc & 7) ^ (row & 7);
    GLOAD_LDS16(BT + (size_t)(n0 + row) * K + kt * BK + kcs * 8, &Bs[b][gc * 8]);
  };

  // prologue: tile 0 in stream order (B*, A0, A2, A1, A3); allow A1,A3 in flight
#pragma unroll
  for (int r = 0; r < BCH; ++r) stB(0, 0, r);
  stA(0, 0, 0); stA(0, 0, 2); stA(0, 0, 1); stA(0, 0, 3);
  asm volatile("s_waitcnt vmcnt(2)" ::: "memory");
  __builtin_amdgcn_sched_barrier(0);
  __builtin_amdgcn_s_barrier();

  const int T = K >> 6;
  for (int t = 0; t < T; ++t) {
    const int b = t & 1;
    const bool more = (t + 1 < T);
    const unsigned short* Ab = As[b];
    const unsigned short* Bb = Bs[b];
    bf16x8 bfr[NREP];
#pragma unroll
    for (int p = 0; p < 4; ++p) {
      const int kk = p >> 1, mh = p & 1;
      if (mh == 0) {
#pragma unroll
        for (int nf = 0; nf < NREP; ++nf) {
          int br = wc * (BN / 4) + nf * 16 + rsel;
          bfr[nf] = *(const bf16x8*)&Bb[br * BK + (((kk * 4 + kgrp) ^ (br & 7)) * 8)];
        }
      }
      bf16x8 af[4];
#pragma unroll
      for (int q = 0; q < 4; ++q) {
        int ar = wr * 128 + (mh * 4 + q) * 16 + rsel;
        af[q] = *(const bf16x8*)&Ab[ar * BK + (((kk * 4 + kgrp) ^ (ar & 7)) * 8)];
      }
      if (more) {
        if constexpr (BN == 256) {
          if (p == 0)      { stB(t + 1, b ^ 1, 0); stB(t + 1, b ^ 1, 1); }
          else if (p == 1) { stB(t + 1, b ^ 1, 2); stB(t + 1, b ^ 1, 3); }
          else if (p == 2) { stA(t + 1, b ^ 1, 0); stA(t + 1, b ^ 1, 2); }
          else             { stA(t + 1, b ^ 1, 1); stA(t + 1, b ^ 1, 3); }
        } else {
          if (p == 0)      { stB(t + 1, b ^ 1, 0); stB(t + 1, b ^ 1, 1); }
          else if (p == 1) { stA(t + 1, b ^ 1, 0); stA(t + 1, b ^ 1, 2); }
          else if (p == 2) { stA(t + 1, b ^ 1, 1); stA(t + 1, b ^ 1, 3); }
        }
      }
      if (p == 0 || p == 3) {
        if (more) asm volatile("s_waitcnt vmcnt(2)" ::: "memory");
        else      asm volatile("s_waitcnt vmcnt(0)" ::: "memory");
      }
      __builtin_amdgcn_sched_barrier(0);
      __builtin_amdgcn_s_barrier();
      asm volatile("s_waitcnt lgkmcnt(0)" ::: "memory");
      __builtin_amdgcn_sched_barrier(0);
      __builtin_amdgcn_s_setprio(1);
#pragma unroll
      for (int q = 0; q < 4; ++q)
#pragma unroll
        for (int nf = 0; nf < NREP; ++nf)
          acc[mh * 4 + q][nf] = mfma32(af[q], bfr[nf], acc[mh * 4 + q][nf]);
      __builtin_amdgcn_s_setprio(0);
      __builtin_amdgcn_sched_barrier(0);
      __builtin_amdgcn_s_barrier();
    }
  }

#pragma unroll
  for (int mf = 0; mf < 8; ++mf) {
#pragma unroll
    for (int nf = 0; nf < NREP; ++nf) {
      const int n = n0 + wc * (BN / 4) + nf * 16 + rsel;
#pragma unroll
      for (int j = 0; j < 4; ++j) {
        const int m = m0 + wr * 128 + mf * 16 + kgrp * 4 + j;
        const size_t idx = (size_t)m * N + n;
        float v = acc[mf][nf][j];
        if constexpr (EPI == EPI_BF16) {
          outb[idx] = f2bu(v);
        } else if constexpr (EPI == EPI_GELU_BF16) {
          v += bias[n];
          v = 0.5f * v * (1.0f + erff(v * 0.70710678118654752f));
          outb[idx] = f2bu(v);
        } else if constexpr (EPI == EPI_RES_F32) {
          outf[idx] = v + resid[idx];
        } else {
          outf[idx] = v + bias[n] + resid[idx];
        }
      }
    }
  }
}

// ---------------- fused causal flash attention ----------------
// Block = FOUR q-tiles {i, 15-i, 16+i, 31-i} x head x batch: 66 compute-units per
// block (perfectly balanced over i=0..7) and ONE K/V staging serves 256 q rows ->
// K/V HBM/L2 traffic halves vs 2-tile pairing. Grid 512 = 2 blocks/CU.
// S^T = K @ Q^T via mfma 16x16x32; P^T stays in registers as the B-frag of
// mfma 16x16x16 for O^T = V^T @ P^T; V read with ds_read_b64_tr_b16, V-frags
// shared by all 4 q-sets. Softmax in log2 domain with defer-rescale (THR=8).

__global__ __launch_bounds__(256, 2) void attn_kernel(
    const unsigned short* __restrict__ QKV,  // [Mz][3072] bf16 (q|k|v, feature h*64+e)
    unsigned short* __restrict__ outA)       // [Mz][Dz]  bf16
{
  __shared__ unsigned short Kt[64 * 64];  // [key][d], 16B d-chunk XOR-swizzled by key&7
  __shared__ unsigned short Vs[64 * 64];  // subtiled for tr16 reads
  const int ii = blockIdx.x;  // 0..7
  const int hh = blockIdx.y;
  const int bb = blockIdx.z;
  const int tid = threadIdx.x;
  const int lane = tid & 63;
  const int w = tid >> 6;
  const int rsel = lane & 15;
  const int kgrp = lane >> 4;
  const int qt[4] = {ii, 15 - ii, 16 + ii, 31 - ii};

  bf16x8 qf0[4], qf1[4];
  int qg[4];
#pragma unroll
  for (int s = 0; s < 4; ++s) {
    qg[s] = qt[s] * 64 + w * 16 + rsel;
    const size_t rowQ = (size_t)(bb * Sz + qg[s]) * 3072 + hh * 64;
    qf0[s] = *(const bf16x8*)&QKV[rowQ + kgrp * 8];
    qf1[s] = *(const bf16x8*)&QKV[rowQ + 32 + kgrp * 8];
  }

  f32x4 accO[4][4] = {};  // [set][df]; O^T row=d=(df*16+kgrp*4+j), col=q=rsel
  float mr[4] = {-INFINITY, -INFINITY, -INFINITY, -INFINITY};
  float lr[4] = {0.0f, 0.0f, 0.0f, 0.0f};

  auto vs3 = (__attribute__((address_space(3))) unsigned short*)Vs;
  const unsigned vbase = (unsigned)(uintptr_t)vs3 + (unsigned)lane * 8u;
  constexpr float SCL = 0.18033688011112042f;  // log2(e)/sqrt(64)

  // S^T + online softmax (log2 domain, defer-rescale) -> P^T bf16 B-frags
  auto proc = [&](const bf16x8& q0, const bf16x8& q1, float& mrun, float& lrun,
                  f32x4* accS, s16x4* pb, bool edge, int qgs, int kb) {
    f32x4 sc[4];
    __builtin_amdgcn_s_setprio(1);
#pragma unroll
    for (int kf = 0; kf < 4; ++kf) {
      int key = kf * 16 + rsel;
      bf16x8 k0 = *(const bf16x8*)&Kt[key * 64 + ((kgrp ^ (key & 7)) * 8)];
      bf16x8 k1 = *(const bf16x8*)&Kt[key * 64 + (((4 + kgrp) ^ (key & 7)) * 8)];
      f32x4 s = {};
      s = mfma32(k0, q0, s);
      s = mfma32(k1, q1, s);
      sc[kf] = s;
    }
    __builtin_amdgcn_s_setprio(0);
    float tmax = -INFINITY;
#pragma unroll
    for (int kf = 0; kf < 4; ++kf)
#pragma unroll
      for (int j = 0; j < 4; ++j) {
        float v = sc[kf][j] * SCL;
        if (edge) {
          int keyg = kb + kf * 16 + kgrp * 4 + j;
          if (keyg > qgs) v = -INFINITY;
        }
        sc[kf][j] = v;
        tmax = fmaxf(tmax, v);
      }
    tmax = fmaxf(tmax, __shfl_xor(tmax, 16));
    tmax = fmaxf(tmax, __shfl_xor(tmax, 32));
    // defer-rescale (T13): skip O/l rescale while max growth stays under 8 (log2 units)
    if (!__all(tmax <= mrun + 8.0f)) {
      const float mnew = fmaxf(mrun, tmax);
      const float corr = exp2f(mrun - mnew);
      lrun *= corr;
#pragma unroll
      for (int df = 0; df < 4; ++df) accS[df] *= corr;
      mrun = mnew;
    }
    float psum = 0.0f;
#pragma unroll
    for (int kf = 0; kf < 4; ++kf) {
      bf16x4 pv;
#pragma unroll
      for (int j = 0; j < 4; ++j) {
        float e = exp2f(sc[kf][j] - mrun);
        psum += e;
        pv[j] = (__bf16)e;  // v_cvt_pk_bf16_f32 pairs
      }
      pb[kf] = __builtin_bit_cast(s16x4, pv);
    }
    psum += __shfl_xor(psum, 16);
    psum += __shfl_xor(psum, 32);
    lrun += psum;
  };

  for (int kt = 0; kt <= qt[3]; ++kt) {
    const int kb = kt * 64;
    if (kt) __syncthreads();  // prev tile's LDS reads done before overwrite
    // stage K: LDS linear, global d-chunk XOR-swizzled by key&7
#pragma unroll
    for (int r = 0; r < 2; ++r) {
      int c = r * 256 + tid;
      int key = c >> 3;
      int dcs = (c & 7) ^ (key & 7);
      GLOAD_LDS16(QKV + (size_t)(bb * Sz + kb + key) * 3072 + 1024 + hh * 64 + dcs * 8,
                  &Kt[c * 8]);
    }
    // stage V: LDS linear; source permuted so LDS holds subtiled layout
#pragma unroll
    for (int r = 0; r < 2; ++r) {
      int c = r * 256 + tid;
      int key = ((c >> 3) & 15) * 4 + ((c >> 1) & 3);
      int d = (c >> 7) * 16 + (c & 1) * 8;
      GLOAD_LDS16(QKV + (size_t)(bb * Sz + kb + key) * 3072 + 2048 + hh * 64 + d,
                  &Vs[c * 8]);
    }
    __syncthreads();

    s16x4 pb[4][4];
#pragma unroll
    for (int s = 0; s < 4; ++s)
      if (kt <= qt[s])
        proc(qf0[s], qf1[s], mr[s], lr[s], accO[s], pb[s], kt == qt[s], qg[s], kb);

    // O^T += V^T @ P^T — V-frags shared by all 4 q-sets
#pragma unroll
    for (int df = 0; df < 4; ++df) {
      unsigned a = vbase + df * 2048;
      s16x4 vf0 = tr16<0>(a);
      s16x4 vf1 = tr16<512>(a);
      s16x4 vf2 = tr16<1024>(a);
      s16x4 vf3 = tr16<1536>(a);
      asm volatile("s_waitcnt lgkmcnt(0)" ::: "memory");
      __builtin_amdgcn_sched_barrier(0);
      __builtin_amdgcn_s_setprio(1);
#pragma unroll
      for (int s = 0; s < 4; ++s) {
        if (kt <= qt[s]) {
          accO[s][df] = mfma16(vf0, pb[s][0], accO[s][df]);
          accO[s][df] = mfma16(vf1, pb[s][1], accO[s][df]);
          accO[s][df] = mfma16(vf2, pb[s][2], accO[s][df]);
          accO[s][df] = mfma16(vf3, pb[s][3], accO[s][df]);
        }
      }
      __builtin_amdgcn_s_setprio(0);
    }
  }

#pragma unroll
  for (int s = 0; s < 4; ++s) {
    const float rl = 1.0f / lr[s];
    const size_t orow = (size_t)(bb * Sz + qg[s]) * Dz + hh * 64;
#pragma unroll
    for (int df = 0; df < 4; ++df) {
      s16x4 o;
#pragma unroll
      for (int j = 0; j < 4; ++j) o[j] = (short)f2bu(accO[s][df][j] * rl);
      *(s16x4*)&outA[orow + df * 16 + kgrp * 4] = o;
    }
  }
}

// ---------------- launch ----------------

extern "C" void kernel_launch(void* const* d_in, const int* in_sizes, int n_in,
                              void* d_out, int out_size, void* d_ws, size_t ws_size,
                              hipStream_t stream) {
  const float* x   = (const float*)d_in[0];
  // d_in[1] = mask (causal, known) — unused
  const float* wq  = (const float*)d_in[2];
  const float* wk  = (const float*)d_in[3];
  const float* wv  = (const float*)d_in[4];
  const float* wo  = (const float*)d_in[5];
  const float* w1  = (const float*)d_in[6];
  const float* b1  = (const float*)d_in[7];
  const float* w2  = (const float*)d_in[8];
  const float* b2  = (const float*)d_in[9];
  const float* g1  = (const float*)d_in[10];
  const float* be1 = (const float*)d_in[11];
  const float* g2  = (const float*)d_in[12];
  const float* be2 = (const float*)d_in[13];
  float* out = (float*)d_out;

  char* ws = (char*)d_ws;
  unsigned short* WqkvT = (unsigned short*)(ws);
  unsigned short* WoT   = (unsigned short*)(ws + 6291456);
  unsigned short* W1T   = (unsigned short*)(ws + 8388608);
  unsigned short* W2T   = (unsigned short*)(ws + 16777216);
  unsigned short* hbuf  = (unsigned short*)(ws + 25165824);
  unsigned short* big   = (unsigned short*)(ws + 41943040);  // QKV, later ff1

  dim3 tb(32, 8);
  pack_qkv<<<768, 256, 0, stream>>>(wq, wk, wv, WqkvT);
  transpose_f32_to_bf16<<<dim3(32, 32), tb, 0, stream>>>(wo, WoT, 1024, 1024);
  transpose_f32_to_bf16<<<dim3(128, 32), tb, 0, stream>>>(w1, W1T, 1024, 4096);
  transpose_f32_to_bf16<<<dim3(32, 128), tb, 0, stream>>>(w2, W2T, 4096, 1024);

  ln_kernel<<<Mz, 256, 0, stream>>>(x, g1, be1, hbuf);
  gemm256<128, EPI_BF16><<<768, 512, 0, stream>>>(
      hbuf, WqkvT, Mz, 3072, 1024, nullptr, nullptr, big, nullptr);
  attn_kernel<<<dim3(8, 16, 4), 256, 0, stream>>>(big, hbuf);
  gemm256<128, EPI_RES_F32><<<256, 512, 0, stream>>>(
      hbuf, WoT, Mz, 1024, 1024, nullptr, x, nullptr, out);
  ln_kernel<<<Mz, 256, 0, stream>>>(out, g2, be2, hbuf);
  gemm256<256, EPI_GELU_BF16><<<512, 512, 0, stream>>>(
      hbuf, W1T, Mz, Fz, 1024, b1, nullptr, big, nullptr);
  gemm256<128, EPI_BIAS_RES_F32><<<256, 512, 0, stream>>>(
      big, W2T, Mz, 1024, Fz, b2, out, nullptr, out);
}